// Round 1
// baseline (34872.574 us; speedup 1.0000x reference)
//
#include <hip/hip_runtime.h>

#define T_STEPS 256
#define FDIM 128
#define HDIM 512

using short8 = __attribute__((ext_vector_type(8))) short;
using f32x4  = __attribute__((ext_vector_type(4))) float;
using fvec4  = __attribute__((ext_vector_type(4))) float;
using ivec4  = __attribute__((ext_vector_type(4))) int;
using uvec2  = __attribute__((ext_vector_type(2))) unsigned int;
using uvec4  = __attribute__((ext_vector_type(4))) unsigned int;

static __device__ __forceinline__ unsigned short f2bf(float f){
  unsigned u = __builtin_bit_cast(unsigned, f);
  u += 0x7fffu + ((u>>16)&1u);
  return (unsigned short)(u>>16);
}
static __device__ __forceinline__ float bf2f(unsigned short h){
  unsigned u = ((unsigned)h)<<16;
  return __builtin_bit_cast(float, u);
}
static __device__ __forceinline__ float fexp2(float x){ return __builtin_amdgcn_exp2f(x); }
static __device__ __forceinline__ float frcp(float x){ return __builtin_amdgcn_rcpf(x); }
static __device__ __forceinline__ float sigm(float x){ return frcp(1.f + fexp2(-1.4426950408889634f*x)); }
static __device__ __forceinline__ float tanh_(float x){
  x = fminf(fmaxf(x, -10.f), 10.f);
  float e = fexp2(2.8853900817779268f*x);
  return (e-1.f)*frcp(e+1.f);
}
static __device__ __forceinline__ f32x4 mfma16(short8 a, short8 b, f32x4 c){
  return __builtin_amdgcn_mfma_f32_16x16x32_bf16(a,b,c,0,0,0);
}
static __device__ __forceinline__ short8 bfrag(const uvec4* __restrict__ W, int frag, int lane){
  return __builtin_bit_cast(short8, W[frag*64+lane]);
}

// Pack fp32 row-major weight [N][K] into bf16 frag-major blob:
// frag = n_tile*(K/32)+k_frag; lane holds B[n=lane&15][k = k_frag*32 + (lane>>4)*8 + j], j=0..7.
__global__ void prep_pack(const float* __restrict__ W, uvec4* __restrict__ blob,
                          int N, int K, int total){
  int t = blockIdx.x*256 + threadIdx.x;
  if (t >= total) return;
  int lane = t & 63, frag = t >> 6;
  int nf = K >> 5;
  int kf = frag % nf, nt = frag / nf;
  int n  = nt*16 + (lane & 15);
  int k0 = kf*32 + ((lane>>4)<<3);
  const float* src = W + (long)n*K + k0;
  unsigned r0 = (unsigned)f2bf(src[0]) | ((unsigned)f2bf(src[1])<<16);
  unsigned r1 = (unsigned)f2bf(src[2]) | ((unsigned)f2bf(src[3])<<16);
  unsigned r2 = (unsigned)f2bf(src[4]) | ((unsigned)f2bf(src[5])<<16);
  unsigned r3 = (unsigned)f2bf(src[6]) | ((unsigned)f2bf(src[7])<<16);
  uvec4 v; v.x=r0; v.y=r1; v.z=r2; v.w=r3;
  blob[t] = v;
}

// Persistent scan kernel: 32 blocks x 512 threads; block owns 16 batch rows for all T steps.
__global__ __launch_bounds__(512, 2) void rits_main(
  const float* __restrict__ values, const int* __restrict__ masks, const float* __restrict__ deltas,
  const float* __restrict__ b_dh, const float* __restrict__ b_dx, const float* __restrict__ b_hr,
  const float* __restrict__ b_fr, const float* __restrict__ b_wc,
  const float* __restrict__ b_ih, const float* __restrict__ b_hh,
  const uvec4* __restrict__ Wdh, const uvec4* __restrict__ Wdx, const uvec4* __restrict__ Whr,
  const uvec4* __restrict__ Wfr, const uvec4* __restrict__ Wwc, const uvec4* __restrict__ Wih,
  const uvec4* __restrict__ Whh,
  float* __restrict__ out)
{
  // LDS: row strides chosen so stride(dwords) % 32 == 4 (2-way-free b128 reads) and 16B-aligned rows.
  __shared__ __align__(16) unsigned short sh_hdec[16*520]; // h*gamma_h, bf16 (K for x_h & W_hh gemms)
  __shared__ __align__(16) float          sh_x[16*132];    // x fp32
  __shared__ __align__(16) unsigned short sh_A2[16*264];   // cols 0..127: gamma_x then c_c; 128..255: m
  __shared__ __align__(16) unsigned short sh_dxc[16*136];  // d (stage2) then x_c (stage3+)
  __shared__ __align__(16) unsigned short sh_xh[16*136];
  __shared__ __align__(16) unsigned short sh_zh[16*136];
  __shared__ __align__(16) unsigned short sh_al[16*136];

  const int tid  = threadIdx.x;
  const int w    = tid >> 6;      // wave 0..7: owns H-slice [w*64, w*64+64)
  const int lane = tid & 63;
  const int quad = lane >> 4;
  const int ln   = lane & 15;
  const int b0   = blockIdx.x << 4;

  const int er = (tid*4) >> 7;    // elementwise row 0..15
  const int ef = (tid*4) & 127;   // elementwise feature (multiple of 4)
  const long ebase0 = ((long)(b0+er)*T_STEPS)*FDIM + ef;

  float hprev[4][4], cst[4][4];   // per-wave persistent h,c state: (col = w*64+ct*16+ln, row = quad*4+i)
  #pragma unroll
  for (int a=0;a<4;++a){
    #pragma unroll
    for (int b=0;b<4;++b){ hprev[a][b]=0.f; cst[a][b]=0.f; }
  }

  // preload t=0 inputs
  fvec4 xv = *(const fvec4*)(values + ebase0);
  ivec4 mv = *(const ivec4*)(masks  + ebase0);
  fvec4 dv = *(const fvec4*)(deltas + ebase0);

  for (int t=0; t<T_STEPS; ++t){
    // ---- stage 1: staged regs -> LDS
    {
      *(fvec4*)&sh_x[er*132+ef] = xv;
      unsigned mlo = (mv.x?0x3F80u:0u) | ((mv.y?0x3F80u:0u)<<16);
      unsigned mhi = (mv.z?0x3F80u:0u) | ((mv.w?0x3F80u:0u)<<16);
      uvec2 mm; mm.x=mlo; mm.y=mhi;
      *(uvec2*)&sh_A2[er*264+128+ef] = mm;
      unsigned dlo = (unsigned)f2bf(dv.x) | ((unsigned)f2bf(dv.y)<<16);
      unsigned dhi = (unsigned)f2bf(dv.z) | ((unsigned)f2bf(dv.w)<<16);
      uvec2 dd; dd.x=dlo; dd.y=dhi;
      *(uvec2*)&sh_dxc[er*136+ef] = dd;
    }
    __syncthreads();

    // ---- stage 2: gamma_h -> h_dec (own H-slice); gamma_x (F-tile w)
    short8 dA[4];
    #pragma unroll
    for (int kf=0;kf<4;++kf)
      dA[kf] = *(const short8*)&sh_dxc[ln*136 + kf*32 + quad*8];
    #pragma unroll
    for (int nt=0; nt<4; ++nt){
      const int ntile = w*4+nt;
      f32x4 acc = {0.f,0.f,0.f,0.f};
      #pragma unroll
      for (int kf=0;kf<4;++kf) acc = mfma16(dA[kf], bfrag(Wdh, ntile*4+kf, lane), acc);
      const float bb = b_dh[ntile*16+ln];
      #pragma unroll
      for (int i=0;i<4;++i){
        float g   = acc[i]+bb;
        float gam = fexp2(-1.4426950408889634f * fmaxf(g, 0.f));  // exp(-relu)
        float hd  = hprev[nt][i]*gam;
        sh_hdec[(quad*4+i)*520 + ntile*16+ln] = f2bf(hd);
      }
    }
    {
      f32x4 acc = {0.f,0.f,0.f,0.f};
      #pragma unroll
      for (int kf=0;kf<4;++kf) acc = mfma16(dA[kf], bfrag(Wdx, w*4+kf, lane), acc);
      const float bb = b_dx[w*16+ln];
      #pragma unroll
      for (int i=0;i<4;++i){
        float g  = acc[i]+bb;
        float gx = fexp2(-1.4426950408889634f * fmaxf(g, 0.f));
        sh_A2[(quad*4+i)*264 + w*16+ln] = f2bf(gx);
      }
    }
    __syncthreads();

    // ---- stage 3: x_h = h_dec@W_hr.T + b ; x_c = m*x+(1-m)*x_h   (F-tile w)
    short8 hA[16];
    #pragma unroll
    for (int kf=0;kf<16;++kf)
      hA[kf] = *(const short8*)&sh_hdec[ln*520 + kf*32 + quad*8];
    {
      f32x4 acc = {0.f,0.f,0.f,0.f};
      #pragma unroll
      for (int kf=0;kf<16;++kf) acc = mfma16(hA[kf], bfrag(Whr, w*16+kf, lane), acc);
      const float bb = b_hr[w*16+ln];
      #pragma unroll
      for (int i=0;i<4;++i){
        int r = quad*4+i, c = w*16+ln;
        float xh = acc[i]+bb;
        float m  = bf2f(sh_A2[r*264+128+c]);
        float xx = sh_x[r*132+c];
        float xc = m*xx + (1.f-m)*xh;
        sh_xh[r*136+c]  = f2bf(xh);
        sh_dxc[r*136+c] = f2bf(xc);  // overwrites d (already consumed into dA)
      }
    }
    __syncthreads();

    // ---- stage 4: z_h = x_c@W_fr.T+b ; alpha = [gamma_x,m]@W_wc.T+b   (F-tile w)
    {
      short8 xcA[4];
      #pragma unroll
      for (int kf=0;kf<4;++kf) xcA[kf] = *(const short8*)&sh_dxc[ln*136 + kf*32 + quad*8];
      f32x4 acc = {0.f,0.f,0.f,0.f};
      #pragma unroll
      for (int kf=0;kf<4;++kf) acc = mfma16(xcA[kf], bfrag(Wfr, w*4+kf, lane), acc);
      const float bb = b_fr[w*16+ln];
      #pragma unroll
      for (int i=0;i<4;++i)
        sh_zh[(quad*4+i)*136 + w*16+ln] = f2bf(acc[i]+bb);

      short8 aA[8];
      #pragma unroll
      for (int kf=0;kf<8;++kf) aA[kf] = *(const short8*)&sh_A2[ln*264 + kf*32 + quad*8];
      f32x4 ac2 = {0.f,0.f,0.f,0.f};
      #pragma unroll
      for (int kf=0;kf<8;++kf) ac2 = mfma16(aA[kf], bfrag(Wwc, w*8+kf, lane), ac2);
      const float b2 = b_wc[w*16+ln];
      #pragma unroll
      for (int i=0;i<4;++i)
        sh_al[(quad*4+i)*136 + w*16+ln] = f2bf(ac2[i]+b2);
    }
    __syncthreads();

    // ---- stage 4b: c_h, c_c -> global out (fp32) + A2 (bf16 gates-A)
    {
      fvec4 o;
      #pragma unroll
      for (int j=0;j<4;++j){
        float al = bf2f(sh_al[er*136+ef+j]);
        float zh = bf2f(sh_zh[er*136+ef+j]);
        float xh = bf2f(sh_xh[er*136+ef+j]);
        float m  = bf2f(sh_A2[er*264+128+ef+j]);
        float xx = sh_x[er*132+ef+j];
        float ch = al*zh + (1.f-al)*xh;
        o[j] = m*xx + (1.f-m)*ch;
      }
      *(fvec4*)(out + ebase0 + (long)t*FDIM) = o;
      uvec2 p;
      p.x = (unsigned)f2bf(o[0]) | ((unsigned)f2bf(o[1])<<16);
      p.y = (unsigned)f2bf(o[2]) | ((unsigned)f2bf(o[3])<<16);
      *(uvec2*)&sh_A2[er*264+ef] = p;
    }
    __syncthreads();

    // ---- stage 5: gates = [c_c,m]@W_ih.T + h_dec@W_hh.T + biases ; LSTM update (own H-slice)
    short8 cA[8];
    #pragma unroll
    for (int kf=0;kf<8;++kf) cA[kf] = *(const short8*)&sh_A2[ln*264 + kf*32 + quad*8];

    if (t+1 < T_STEPS){  // prefetch next step's inputs; latency hidden by stage-5 MFMA pile
      long nb = ebase0 + (long)(t+1)*FDIM;
      xv = *(const fvec4*)(values + nb);
      mv = *(const ivec4*)(masks  + nb);
      dv = *(const fvec4*)(deltas + nb);
    }

    #pragma unroll
    for (int ct=0; ct<4; ++ct){
      const int colt = w*4+ct;  // H-tile 0..31
      f32x4 ai={0.f,0.f,0.f,0.f}, af={0.f,0.f,0.f,0.f}, ag={0.f,0.f,0.f,0.f}, ao={0.f,0.f,0.f,0.f};
      #pragma unroll
      for (int kf=0;kf<8;++kf){
        ai = mfma16(cA[kf], bfrag(Wih, (0*32+colt)*8+kf, lane), ai);
        af = mfma16(cA[kf], bfrag(Wih, (1*32+colt)*8+kf, lane), af);
        ag = mfma16(cA[kf], bfrag(Wih, (2*32+colt)*8+kf, lane), ag);
        ao = mfma16(cA[kf], bfrag(Wih, (3*32+colt)*8+kf, lane), ao);
      }
      #pragma unroll
      for (int kf=0;kf<16;++kf){
        ai = mfma16(hA[kf], bfrag(Whh, (0*32+colt)*16+kf, lane), ai);
        af = mfma16(hA[kf], bfrag(Whh, (1*32+colt)*16+kf, lane), af);
        ag = mfma16(hA[kf], bfrag(Whh, (2*32+colt)*16+kf, lane), ag);
        ao = mfma16(hA[kf], bfrag(Whh, (3*32+colt)*16+kf, lane), ao);
      }
      const int n0 = colt*16+ln;
      const float bi  = b_ih[n0]      + b_hh[n0];
      const float bff = b_ih[512+n0]  + b_hh[512+n0];
      const float bg  = b_ih[1024+n0] + b_hh[1024+n0];
      const float bo  = b_ih[1536+n0] + b_hh[1536+n0];
      #pragma unroll
      for (int i=0;i<4;++i){
        float ig = sigm(ai[i]+bi);
        float fg = sigm(af[i]+bff);
        float gg = tanh_(ag[i]+bg);
        float og = sigm(ao[i]+bo);
        float cn = fg*cst[ct][i] + ig*gg;
        float hn = og*tanh_(cn);
        cst[ct][i]  = cn;
        hprev[ct][i] = hn;
      }
    }
    __syncthreads();
  }
}

// ws blob offsets (bytes), bf16 frag-major
#define OFF_WDH 0u
#define OFF_WDX (OFF_WDH + 512u*128u*2u)
#define OFF_WHR (OFF_WDX + 128u*128u*2u)
#define OFF_WFR (OFF_WHR + 128u*512u*2u)
#define OFF_WWC (OFF_WFR + 128u*128u*2u)
#define OFF_WIH (OFF_WWC + 128u*256u*2u)
#define OFF_WHH (OFF_WIH + 2048u*256u*2u)
#define WS_NEED (OFF_WHH + 2048u*512u*2u)

extern "C" void kernel_launch(void* const* d_in, const int* in_sizes, int n_in,
                              void* d_out, int out_size, void* d_ws, size_t ws_size,
                              hipStream_t stream) {
  const float* values = (const float*)d_in[0];
  const int*   masks  = (const int*)  d_in[1];
  const float* deltas = (const float*)d_in[2];
  const float* W_dh = (const float*)d_in[3];  const float* b_dh = (const float*)d_in[4];
  const float* W_dx = (const float*)d_in[5];  const float* b_dx = (const float*)d_in[6];
  const float* W_hr = (const float*)d_in[7];  const float* b_hr = (const float*)d_in[8];
  const float* W_fr = (const float*)d_in[9];  const float* b_fr = (const float*)d_in[10];
  const float* W_wc = (const float*)d_in[11]; const float* b_wc = (const float*)d_in[12];
  const float* W_ih = (const float*)d_in[13]; const float* W_hh = (const float*)d_in[14];
  const float* b_ih = (const float*)d_in[15]; const float* b_hh = (const float*)d_in[16];

  if (ws_size < (size_t)WS_NEED) return;  // need ~3.5 MB scratch for bf16 weight blobs

  char* ws = (char*)d_ws;
  uvec4* bWdh = (uvec4*)(ws + OFF_WDH);
  uvec4* bWdx = (uvec4*)(ws + OFF_WDX);
  uvec4* bWhr = (uvec4*)(ws + OFF_WHR);
  uvec4* bWfr = (uvec4*)(ws + OFF_WFR);
  uvec4* bWwc = (uvec4*)(ws + OFF_WWC);
  uvec4* bWih = (uvec4*)(ws + OFF_WIH);
  uvec4* bWhh = (uvec4*)(ws + OFF_WHH);

  struct PW { const float* W; uvec4* blob; int N; int K; };
  PW pw[7] = {
    { W_dh, bWdh,  512, 128 }, { W_dx, bWdx,  128, 128 },
    { W_hr, bWhr,  128, 512 }, { W_fr, bWfr,  128, 128 },
    { W_wc, bWwc,  128, 256 }, { W_ih, bWih, 2048, 256 },
    { W_hh, bWhh, 2048, 512 },
  };
  for (int i=0;i<7;++i){
    int total  = (pw[i].N/16)*(pw[i].K/32)*64;
    int blocks = (total + 255)/256;
    prep_pack<<<blocks, 256, 0, stream>>>(pw[i].W, pw[i].blob, pw[i].N, pw[i].K, total);
  }

  rits_main<<<dim3(32), dim3(512), 0, stream>>>(
    values, masks, deltas,
    b_dh, b_dx, b_hr, b_fr, b_wc, b_ih, b_hh,
    bWdh, bWdx, bWhr, bWfr, bWwc, bWih, bWhh,
    (float*)d_out);
}

// Round 3
// 11616.134 us; speedup vs baseline: 3.0021x; 3.0021x over previous
//
#include <hip/hip_runtime.h>

// ---------------------------------------------------------------------------
// RITS recurrent scan, model-parallel persistent kernel.
// 8 groups x 64 batch rows; each group = 32 blocks (1 per CU).
// Block (g, r): owns H-slice [16r,16r+16) (LSTM gates + state + W_dh rows) and
// F-tile ft = r&7 (x_h/x_c/z_h/alpha/c_h/c_c chain), replicated 4x (rep = r>>3).
// All weights live in VGPRs/LDS (loaded once). Per-step activation exchange
// between the 32 blocks goes through global memory, made coherent by
// release/acquire group barriers (buffer_wbl2/buffer_inv via agent fences).
// Exchange data uses PLAIN stores (byte-granular write masks; no sub-word
// atomic RMW hazard) and plain 16B frag loads. Buffers double-buffered by
// t-parity so 3 barriers/step suffice.
// ---------------------------------------------------------------------------

using short8 = __attribute__((ext_vector_type(8))) short;
using f32x4  = __attribute__((ext_vector_type(4))) float;
using fvec4  = __attribute__((ext_vector_type(4))) float;
using ivec4  = __attribute__((ext_vector_type(4))) int;
using uvec4  = __attribute__((ext_vector_type(4))) unsigned int;

#define LOG2E 1.4426950408889634f

union U8 {
  unsigned u[4];
  unsigned long long q[2];
  short8 s;
  uvec4 v;
};

static __device__ __forceinline__ unsigned short f2bf(float f){
  unsigned u = __builtin_bit_cast(unsigned, f);
  u += 0x7fffu + ((u>>16)&1u);
  return (unsigned short)(u>>16);
}
static __device__ __forceinline__ float fexp2(float x){ return __builtin_amdgcn_exp2f(x); }
static __device__ __forceinline__ float frcp(float x){ return __builtin_amdgcn_rcpf(x); }
static __device__ __forceinline__ float sigm(float x){ return frcp(1.f + fexp2(-LOG2E*x)); }
static __device__ __forceinline__ float tanh_(float x){
  x = fminf(fmaxf(x,-10.f),10.f);
  float e = fexp2(2.f*LOG2E*x);
  return (e-1.f)*frcp(e+1.f);
}
static __device__ __forceinline__ f32x4 mfma16(short8 a, short8 b, f32x4 c){
  return __builtin_amdgcn_mfma_f32_16x16x32_bf16(a,b,c,0,0,0);
}
static __device__ __forceinline__ short8 frag_of(uvec4 v){ return __builtin_bit_cast(short8, v); }

// plain 16B frag load from exchange buffer (coherence via barrier fences)
static __device__ __forceinline__ short8 ex_frag(const unsigned short* p){
  U8 u; u.v = *(const uvec4*)p;
  return u.s;
}

// scatter one bf16 value at logical (row-in-tile rl, k-dim kk) into a
// 16x16x32 A-frag-major exchange region with KF k-frags, m-tile mt.
static __device__ __forceinline__ void scatter_ex(unsigned short* exbuf, int mt, int KF,
                                                  int rl, int kk, float val){
  int kf = kk>>5, ko = kk&31;
  int L = rl + 16*(ko>>3);
  long off = ((long)(mt*KF+kf)*64 + L)*8 + (ko&7);
  exbuf[off] = f2bf(val);
}

// mask A-frag built on the fly from int mask input (values are exactly 0/1).
static __device__ __forceinline__ short8 m_frag(const int* __restrict__ masks, long base, int col0){
  ivec4 a = *(const ivec4*)(masks + base + col0);
  ivec4 b = *(const ivec4*)(masks + base + col0 + 4);
  U8 t;
  t.u[0] = (a.x?0x3F80u:0u) | ((a.y?0x3F80u:0u)<<16);
  t.u[1] = (a.z?0x3F80u:0u) | ((a.w?0x3F80u:0u)<<16);
  t.u[2] = (b.x?0x3F80u:0u) | ((b.y?0x3F80u:0u)<<16);
  t.u[3] = (b.z?0x3F80u:0u) | ((b.w?0x3F80u:0u)<<16);
  return t.s;
}

// Group barrier with proper device-scope release/acquire.
// Producer side: __syncthreads drains each wave's vmcnt (stores in XCD L2,
// L1 is write-through); thread0's RELEASE fence emits buffer_wbl2 sc1 +
// vmcnt(0) flushing the XCD L2 to the memory-side LLC before the counter
// bump. Consumer side: ACQUIRE fence emits buffer_inv invalidating this CU's
// L1 + XCD L2, so loads after the closing __syncthreads read fresh LLC data.
static __device__ __forceinline__ void group_barrier(unsigned* ctr, unsigned tgt){
  __syncthreads();
  if (threadIdx.x == 0){
    __builtin_amdgcn_fence(__ATOMIC_RELEASE, "agent");
    __hip_atomic_fetch_add(ctr, 1u, __ATOMIC_RELAXED, __HIP_MEMORY_SCOPE_AGENT);
    while (__hip_atomic_load(ctr, __ATOMIC_RELAXED, __HIP_MEMORY_SCOPE_AGENT) < tgt){
      __builtin_amdgcn_s_sleep(1);
    }
    __builtin_amdgcn_fence(__ATOMIC_ACQUIRE, "agent");
  }
  __syncthreads();
}

// ---------------------------------------------------------------------------
// Weight packing. B-frag layout (16x16x32): frag f holds B[n=lane&15][k = kf*32
// + (lane>>4)*8 + j], 16B/lane. Generic: rows of src tiled by 16 (tile*16+n).
// ---------------------------------------------------------------------------
__global__ void pack_generic(const float* __restrict__ src, uvec4* __restrict__ dst,
                             int KF, int srcK, int total){
  int t = blockIdx.x*256 + threadIdx.x;
  if (t >= total) return;
  int lane = t & 63, frag = t >> 6;
  int kf = frag % KF, tile = frag / KF;
  int n  = tile*16 + (lane & 15);
  int k0 = kf*32 + ((lane>>4)<<3);
  const float* s = src + (long)n*srcK + k0;
  U8 o;
  o.u[0] = (unsigned)f2bf(s[0]) | ((unsigned)f2bf(s[1])<<16);
  o.u[1] = (unsigned)f2bf(s[2]) | ((unsigned)f2bf(s[3])<<16);
  o.u[2] = (unsigned)f2bf(s[4]) | ((unsigned)f2bf(s[5])<<16);
  o.u[3] = (unsigned)f2bf(s[6]) | ((unsigned)f2bf(s[7])<<16);
  dst[t] = o.v;
}

// Gates blob: per role r (0..31), 4 n-tiles x 24 k-frags. Output col c=nt*16+n
// maps to (h_local=c>>2, gate=c&3), weight row R = gate*512 + r*16 + h_local.
// K order: [c_c 0..127 (W_ih), m 128..255 (W_ih), h_dec 0..511 (W_hh)].
__global__ void pack_gates(const float* __restrict__ Wih, const float* __restrict__ Whh,
                           uvec4* __restrict__ dst){
  int t = blockIdx.x*256 + threadIdx.x;
  if (t >= 3072*64) return;
  int lane = t & 63, frag = t >> 6;
  int kf = frag % 24; int rnt = frag / 24;
  int nt = rnt & 3; int r = rnt >> 2;
  int c = nt*16 + (lane & 15);
  int Rrow = (c & 3)*512 + r*16 + (c >> 2);
  int k = kf*32 + ((lane>>4)<<3);
  const float* s = (kf < 8) ? (Wih + (long)Rrow*256 + k)
                            : (Whh + (long)Rrow*512 + (k - 256));
  U8 o;
  o.u[0] = (unsigned)f2bf(s[0]) | ((unsigned)f2bf(s[1])<<16);
  o.u[1] = (unsigned)f2bf(s[2]) | ((unsigned)f2bf(s[3])<<16);
  o.u[2] = (unsigned)f2bf(s[4]) | ((unsigned)f2bf(s[5])<<16);
  o.u[3] = (unsigned)f2bf(s[6]) | ((unsigned)f2bf(s[7])<<16);
  dst[t] = o.v;
}

// ---------------------------------------------------------------------------
__global__ __launch_bounds__(512,2) void rits_main(
  const float* __restrict__ values, const int* __restrict__ masks, const float* __restrict__ deltas,
  const float* __restrict__ b_dh, const float* __restrict__ b_dx, const float* __restrict__ b_hr,
  const float* __restrict__ b_fr, const float* __restrict__ b_wc,
  const float* __restrict__ b_ih, const float* __restrict__ b_hh,
  const uvec4* __restrict__ BG, const uvec4* __restrict__ BDH, const uvec4* __restrict__ BHR,
  const uvec4* __restrict__ BDX, const uvec4* __restrict__ BFR, const uvec4* __restrict__ BWC,
  unsigned short* __restrict__ EX, unsigned* __restrict__ BAR,
  float* __restrict__ out)
{
  __shared__ __align__(16) uvec4 sh_whr[16*64];      // 16KB  W_hr tile frags
  __shared__ __align__(16) uvec4 sh_wwc[8*64];       // 8KB   W_wc tile frags
  __shared__ __align__(16) float sh_gbuf[64*68];     // 17KB  gates f32 (+x_h partials overlay)
  __shared__ __align__(16) float sh_za[4*1088];      // 17KB  z_h / alpha partials [kh*2+za][row*17+ln]

  const int tid = threadIdx.x;
  const int w = tid>>6, lane = tid&63, quad = lane>>4, ln = lane&15;
  const int g = blockIdx.x >> 5, r = blockIdx.x & 31, ft = r & 7, rep = r >> 3;

  const int mtp = w & 1, ntp = (w>>1) & 1, kh = w >> 2;  // P3 roles
  const int mtw = w & 3, khw = w >> 2;                   // P0/P1/P2 roles
  const bool isH = (w < 4);

  // ---- static weight registers
  uvec4 gB[24];
  #pragma unroll
  for (int ntL=0; ntL<2; ++ntL)
    #pragma unroll
    for (int kfL=0; kfL<12; ++kfL)
      gB[ntL*12+kfL] = BG[ (((long)(r*4 + (2*ntp+ntL))*24) + (12*kh+kfL))*64 + lane ];
  uvec4 pB[4];
  #pragma unroll
  for (int kf=0; kf<4; ++kf)
    pB[kf] = isH ? BDH[(r*4+kf)*64+lane] : BDX[(ft*4+kf)*64+lane];
  uvec4 fB[2];
  #pragma unroll
  for (int kk=0; kk<2; ++kk)
    fB[kk] = BFR[(ft*4 + 2*khw + kk)*64 + lane];

  for (int idx = tid; idx < 16*64; idx += 512) sh_whr[idx] = BHR[ft*16*64 + idx];
  for (int idx = tid; idx < 8*64;  idx += 512) sh_wwc[idx] = BWC[ft*8*64 + idx];

  const float bias_p  = isH ? b_dh[r*16+ln] : b_dx[ft*16+ln];
  const float bias_hr = b_hr[ft*16+ln];
  const float bias_fr = b_fr[ft*16+ln];
  const float bias_wc = b_wc[ft*16+ln];
  float gbias[2];
  #pragma unroll
  for (int ntL=0; ntL<2; ++ntL){
    int c = (2*ntp+ntL)*16 + ln;
    int Rr = (c&3)*512 + r*16 + (c>>2);
    gbias[ntL] = b_ih[Rr] + b_hh[Rr];
  }

  float hs[4] = {0,0,0,0}, cs[4] = {0,0,0,0};

  unsigned* ctr = BAR + g*16;
  unsigned seq = 0;

  unsigned short* const exb0 = EX + (long)g*57344;          // parity 0
  unsigned short* const exb1 = EX + (long)(8+g)*57344;      // parity 1

  const long rowA = (long)(g*64 + mtw*16 + ln);             // A-frag row (m = ln) for this wave

  __syncthreads();

  for (int t=0; t<256; ++t){
    unsigned short* const exh  = (t & 1) ? exb1 : exb0;
    unsigned short* const exxc = exh + 32768;
    unsigned short* const exgx = exh + 40960;
    unsigned short* const excc = exh + 49152;
    const long ibase = (rowA*256 + t)*128;                  // [B][T][F] element offset

    // ================= P0: gamma_h / h_dec (waves 0-3), gamma_x (waves 4-7)
    {
      short8 dA[4];
      #pragma unroll
      for (int kf=0; kf<4; ++kf){
        int c0 = kf*32 + quad*8;
        fvec4 lo = *(const fvec4*)(deltas + ibase + c0);
        fvec4 hi = *(const fvec4*)(deltas + ibase + c0 + 4);
        U8 p8;
        p8.u[0] = (unsigned)f2bf(lo.x) | ((unsigned)f2bf(lo.y)<<16);
        p8.u[1] = (unsigned)f2bf(lo.z) | ((unsigned)f2bf(lo.w)<<16);
        p8.u[2] = (unsigned)f2bf(hi.x) | ((unsigned)f2bf(hi.y)<<16);
        p8.u[3] = (unsigned)f2bf(hi.z) | ((unsigned)f2bf(hi.w)<<16);
        dA[kf] = p8.s;
      }
      f32x4 acc = {0.f,0.f,0.f,0.f};
      #pragma unroll
      for (int kf=0; kf<4; ++kf) acc = mfma16(dA[kf], frag_of(pB[kf]), acc);

      if (isH){
        int kk = r*16 + ln;
        #pragma unroll
        for (int i=0;i<4;++i){
          float gam = fexp2(-LOG2E * fmaxf(acc[i]+bias_p, 0.f));
          float hd  = hs[i]*gam;
          scatter_ex(exh, mtw, 16, quad*4+i, kk, hd);
        }
      } else if (rep == 0){
        int kk = ft*16 + ln;
        #pragma unroll
        for (int i=0;i<4;++i){
          float gx = fexp2(-LOG2E * fmaxf(acc[i]+bias_p, 0.f));
          scatter_ex(exgx, mtw, 4, quad*4+i, kk, gx);
        }
      }
    }
    group_barrier(ctr, 32u*(++seq));

    // ================= P1: x_h partials (all waves), then x_c (waves 0-3)
    {
      f32x4 axh = {0.f,0.f,0.f,0.f};
      #pragma unroll
      for (int kk2=0; kk2<8; ++kk2){
        int kf = 8*khw + kk2;
        short8 a = ex_frag(exh + ((long)(mtw*16+kf)*64 + lane)*8);
        axh = mfma16(a, frag_of(sh_whr[kf*64+lane]), axh);
      }
      #pragma unroll
      for (int i=0;i<4;++i)
        sh_gbuf[khw*1088 + (mtw*16+quad*4+i)*17 + ln] = axh[i];
    }
    __syncthreads();

    float xh_r[4], xx_r[4];
    int   m_r[4];
    if (isH){
      #pragma unroll
      for (int i=0;i<4;++i){
        int row = mtw*16 + quad*4 + i;
        float xh = sh_gbuf[row*17+ln] + sh_gbuf[1088 + row*17+ln] + bias_hr;
        long io = ((long)(g*64+row)*256 + t)*128 + ft*16 + ln;
        int   m  = masks[io];
        float xx = values[io];
        float xc = m ? xx : xh;
        xh_r[i]=xh; xx_r[i]=xx; m_r[i]=m;
        if (rep == 0)
          scatter_ex(exxc, mtw, 4, quad*4+i, ft*16+ln, xc);
      }
    }
    group_barrier(ctr, 32u*(++seq));

    // ================= P2: z_h & alpha partials, then c_h/c_c + output (waves 0-3)
    {
      f32x4 az = {0.f,0.f,0.f,0.f};
      #pragma unroll
      for (int kk2=0; kk2<2; ++kk2){
        int kf = 2*khw + kk2;
        short8 a = ex_frag(exxc + ((long)(mtw*4+kf)*64 + lane)*8);
        az = mfma16(a, frag_of(fB[kk2]), az);
      }
      f32x4 aa = {0.f,0.f,0.f,0.f};
      if (khw == 0){
        #pragma unroll
        for (int kk2=0; kk2<4; ++kk2){
          short8 a = ex_frag(exgx + ((long)(mtw*4+kk2)*64 + lane)*8);
          aa = mfma16(a, frag_of(sh_wwc[kk2*64+lane]), aa);
        }
      } else {
        #pragma unroll
        for (int kk2=0; kk2<4; ++kk2){
          short8 a = m_frag(masks, ibase, kk2*32 + quad*8);
          aa = mfma16(a, frag_of(sh_wwc[(4+kk2)*64+lane]), aa);
        }
      }
      #pragma unroll
      for (int i=0;i<4;++i){
        int row = mtw*16 + quad*4 + i;
        sh_za[(khw*2+0)*1088 + row*17 + ln] = az[i];
        sh_za[(khw*2+1)*1088 + row*17 + ln] = aa[i];
      }
    }
    __syncthreads();

    if (isH){
      #pragma unroll
      for (int i=0;i<4;++i){
        int row = mtw*16 + quad*4 + i;
        float zh = sh_za[row*17+ln] + sh_za[2*1088 + row*17+ln] + bias_fr;
        float al = sh_za[1088 + row*17+ln] + sh_za[3*1088 + row*17+ln] + bias_wc;
        float ch = al*zh + (1.f-al)*xh_r[i];
        float cc = m_r[i] ? xx_r[i] : ch;
        if (rep == 0){
          long oo = ((long)(g*64+row)*256 + t)*128 + ft*16 + ln;
          out[oo] = cc;
          scatter_ex(excc, mtw, 4, quad*4+i, ft*16+ln, cc);
        }
      }
    }
    group_barrier(ctr, 32u*(++seq));

    // ================= P3: gates GEMM ([c_c,m]@W_ih.T + h_dec@W_hh.T), LSTM update
    {
      f32x4 acc4[2][2];
      #pragma unroll
      for (int a=0;a<2;++a)
        #pragma unroll
        for (int b=0;b<2;++b){ acc4[a][b][0]=0.f; acc4[a][b][1]=0.f; acc4[a][b][2]=0.f; acc4[a][b][3]=0.f; }

      const long mb0 = ((long)(g*64 + (2*mtp+0)*16 + ln)*256 + t)*128;
      const long mb1 = mb0 + (long)16*256*128;

      if (kh == 0){
        #pragma unroll
        for (int kfL=0; kfL<12; ++kfL){
          short8 a0, a1;
          if (kfL < 4){
            a0 = ex_frag(excc + ((long)((2*mtp+0)*4+kfL)*64 + lane)*8);
            a1 = ex_frag(excc + ((long)((2*mtp+1)*4+kfL)*64 + lane)*8);
          } else if (kfL < 8){
            int c0 = (kfL-4)*32 + quad*8;
            a0 = m_frag(masks, mb0, c0);
            a1 = m_frag(masks, mb1, c0);
          } else {
            a0 = ex_frag(exh + ((long)((2*mtp+0)*16+(kfL-8))*64 + lane)*8);
            a1 = ex_frag(exh + ((long)((2*mtp+1)*16+(kfL-8))*64 + lane)*8);
          }
          acc4[0][0] = mfma16(a0, frag_of(gB[kfL]),    acc4[0][0]);
          acc4[0][1] = mfma16(a0, frag_of(gB[12+kfL]), acc4[0][1]);
          acc4[1][0] = mfma16(a1, frag_of(gB[kfL]),    acc4[1][0]);
          acc4[1][1] = mfma16(a1, frag_of(gB[12+kfL]), acc4[1][1]);
        }
      } else {
        #pragma unroll
        for (int kfL=0; kfL<12; ++kfL){
          int hk = 4 + kfL;
          short8 a0 = ex_frag(exh + ((long)((2*mtp+0)*16+hk)*64 + lane)*8);
          short8 a1 = ex_frag(exh + ((long)((2*mtp+1)*16+hk)*64 + lane)*8);
          acc4[0][0] = mfma16(a0, frag_of(gB[kfL]),    acc4[0][0]);
          acc4[0][1] = mfma16(a0, frag_of(gB[12+kfL]), acc4[0][1]);
          acc4[1][0] = mfma16(a1, frag_of(gB[kfL]),    acc4[1][0]);
          acc4[1][1] = mfma16(a1, frag_of(gB[12+kfL]), acc4[1][1]);
        }
      }

      if (kh == 0){
        #pragma unroll
        for (int mtL=0;mtL<2;++mtL)
          #pragma unroll
          for (int ntL=0;ntL<2;++ntL)
            #pragma unroll
            for (int i=0;i<4;++i){
              int row = (2*mtp+mtL)*16 + quad*4 + i;
              int col = (2*ntp+ntL)*16 + ln;
              sh_gbuf[row*68 + col] = acc4[mtL][ntL][i] + gbias[ntL];
            }
      }
      __syncthreads();
      if (kh == 1){
        #pragma unroll
        for (int mtL=0;mtL<2;++mtL)
          #pragma unroll
          for (int ntL=0;ntL<2;++ntL)
            #pragma unroll
            for (int i=0;i<4;++i){
              int row = (2*mtp+mtL)*16 + quad*4 + i;
              int col = (2*ntp+ntL)*16 + ln;
              sh_gbuf[row*68 + col] += acc4[mtL][ntL][i];
            }
      }
      __syncthreads();

      if (isH){
        #pragma unroll
        for (int i=0;i<4;++i){
          int row = mtw*16 + quad*4 + i;
          f32x4 gv = *(const f32x4*)&sh_gbuf[row*68 + 4*ln];
          float ig = sigm(gv[0]);
          float fg = sigm(gv[1]);
          float gg = tanh_(gv[2]);
          float og = sigm(gv[3]);
          cs[i] = fg*cs[i] + ig*gg;
          hs[i] = og*tanh_(cs[i]);
        }
      }
    }
    // no barrier: exchange buffers double-buffered by t-parity
  }
}

// ---------------------------------------------------------------------------
// Workspace layout (bytes)
#define OFF_G   0u
#define SZ_G    3145728u              // 32 roles x 4nt x 24kf x 1KB
#define OFF_DH  (OFF_G + SZ_G)
#define SZ_DH   131072u               // 32 x 4 x 1KB
#define OFF_HR  (OFF_DH + SZ_DH)
#define SZ_HR   131072u               // 8 x 16 x 1KB
#define OFF_DX  (OFF_HR + SZ_HR)
#define SZ_DX   32768u
#define OFF_FR  (OFF_DX + SZ_DX)
#define SZ_FR   32768u
#define OFF_WC  (OFF_FR + SZ_FR)
#define SZ_WC   65536u
#define OFF_EX  (OFF_WC + SZ_WC)
#define SZ_EX   1835008u              // 2 parity x 8 groups x 112KB
#define OFF_BAR (OFF_EX + SZ_EX)
#define SZ_BAR  512u
#define WS_NEED (OFF_BAR + SZ_BAR)

extern "C" void kernel_launch(void* const* d_in, const int* in_sizes, int n_in,
                              void* d_out, int out_size, void* d_ws, size_t ws_size,
                              hipStream_t stream) {
  const float* values = (const float*)d_in[0];
  const int*   masks  = (const int*)  d_in[1];
  const float* deltas = (const float*)d_in[2];
  const float* W_dh = (const float*)d_in[3];  const float* b_dh = (const float*)d_in[4];
  const float* W_dx = (const float*)d_in[5];  const float* b_dx = (const float*)d_in[6];
  const float* W_hr = (const float*)d_in[7];  const float* b_hr = (const float*)d_in[8];
  const float* W_fr = (const float*)d_in[9];  const float* b_fr = (const float*)d_in[10];
  const float* W_wc = (const float*)d_in[11]; const float* b_wc = (const float*)d_in[12];
  const float* W_ih = (const float*)d_in[13]; const float* W_hh = (const float*)d_in[14];
  const float* b_ih = (const float*)d_in[15]; const float* b_hh = (const float*)d_in[16];

  if (ws_size < (size_t)WS_NEED) return;

  char* ws = (char*)d_ws;
  uvec4* BG  = (uvec4*)(ws + OFF_G);
  uvec4* BDH = (uvec4*)(ws + OFF_DH);
  uvec4* BHR = (uvec4*)(ws + OFF_HR);
  uvec4* BDX = (uvec4*)(ws + OFF_DX);
  uvec4* BFR = (uvec4*)(ws + OFF_FR);
  uvec4* BWC = (uvec4*)(ws + OFF_WC);
  unsigned short* EX = (unsigned short*)(ws + OFF_EX);
  unsigned* BAR = (unsigned*)(ws + OFF_BAR);

  pack_gates<<<768, 256, 0, stream>>>(W_ih, W_hh, BG);
  pack_generic<<<32, 256, 0, stream>>>(W_dh, BDH, 4, 128, 32*4*64);
  pack_generic<<<32, 256, 0, stream>>>(W_hr, BHR, 16, 512, 8*16*64);
  pack_generic<<<8, 256, 0, stream>>>(W_dx, BDX, 4, 128, 8*4*64);
  pack_generic<<<8, 256, 0, stream>>>(W_fr, BFR, 4, 128, 8*4*64);
  pack_generic<<<16, 256, 0, stream>>>(W_wc, BWC, 8, 256, 8*8*64);
  hipMemsetAsync(ws + OFF_BAR, 0, SZ_BAR, stream);

  rits_main<<<dim3(256), dim3(512), 0, stream>>>(
    values, masks, deltas,
    b_dh, b_dx, b_hr, b_fr, b_wc, b_ih, b_hh,
    BG, BDH, BHR, BDX, BFR, BWC,
    EX, BAR,
    (float*)d_out);
}